// Round 7
// baseline (129.671 us; speedup 1.0000x reference)
//
#include <hip/hip_runtime.h>
#include <stdint.h>

#define T_LEN 2048

typedef __attribute__((ext_vector_type(8))) short bf16x8;
typedef __attribute__((ext_vector_type(16))) float f32x16;

// RNE fp32 pair -> packed bf16x2 (inputs finite normals)
static __device__ __forceinline__ unsigned pack_bf16(float a, float b) {
    unsigned ua = __float_as_uint(a);
    unsigned ub = __float_as_uint(b);
    ua = (ua + 0x7fffu + ((ua >> 16) & 1u)) >> 16;
    ub = (ub + 0x7fffu + ((ub >> 16) & 1u));
    return (ua & 0xffffu) | (ub & 0xffff0000u);
}

// async global->LDS DMA, 16 B/lane: LDS dest = wave-uniform base + lane*16
static __device__ __forceinline__ void async16(const void* g, void* l) {
    __builtin_amdgcn_global_load_lds(
        (const __attribute__((address_space(1))) unsigned int*)g,
        (__attribute__((address_space(3))) unsigned int*)l, 16, 0, 0);
}

// 2^x on the transcendental pipe (scores carry log2e folded in from prepack)
static __device__ __forceinline__ float fexp2(float x) {
#if __has_builtin(__builtin_amdgcn_exp2f)
    return __builtin_amdgcn_exp2f(x);
#else
    float r; asm("v_exp_f32 %0, %1" : "=v"(r) : "v"(x)); return r;
#endif
}

// v_permlane32_swap_b32 a, b (in-place, inline asm; HW-verified R6):
//   a_new = {a.lo, b.lo}, b_new = {a.hi, b.hi}  (a.hi <-> b.lo)
static __device__ __forceinline__ void swap32(unsigned& a, unsigned& b) {
    asm("v_permlane32_swap_b32 %0, %1" : "+v"(a), "+v"(b));
}

// ---------------------------------------------------------------------------
// Prepack (unchanged from R6 / 128.9us passing version):
//   Q: ws+0     bf16 [head][t 0..2047][swz c]  rows 128B, scaled 0.125*log2(e)
//   K: ws+8MB   bf16 [head][s 0..2047][swz c]  rows 128B
//   V: ws+16MB  bf16 [head][sTile(64)][c][swz s] rows 128B
// ---------------------------------------------------------------------------
__global__ __launch_bounds__(256)
void prepack(const float* __restrict__ qkv, char* __restrict__ ws)
{
    __shared__ float tile[64 * 130];
    const int tid = threadIdx.x;
    const int b = blockIdx.x;

    if (b < 1024) {                       // ---- Q / K transpose
        const int isK  = b >> 9;
        const int bb   = b & 511;
        const int head = bb >> 4, chunk = bb & 15;
        const float* src = qkv + (size_t)head * 192 * T_LEN
                               + (size_t)(isK ? 64 : 0) * T_LEN;
        const int t0g = chunk * 128;
        const float scale = isK ? 1.0f : 0.18033688f;
#pragma unroll
        for (int i = 0; i < 8; ++i) {
            int p = i * 256 + tid;
            int t4 = p & 31, c = p >> 5;
            float4 v = *(const float4*)(src + (size_t)c * T_LEN + t0g + 4 * t4);
            int a = c * 130 + 4 * t4;
            *(float2*)&tile[a]     = make_float2(v.x, v.y);
            *(float2*)&tile[a + 2] = make_float2(v.z, v.w);
        }
        __syncthreads();
        unsigned* dst = (unsigned*)ws + (size_t)isK * 2097152
                      + (size_t)head * 65536 + (size_t)t0g * 32;
#pragma unroll
        for (int i = 0; i < 16; ++i) {
            int cp = tid & 31, t = i * 8 + (tid >> 5);
            float f0 = tile[(2 * cp) * 130 + t] * scale;
            float f1 = tile[(2 * cp + 1) * 130 + t] * scale;
            dst[t * 32 + (((cp >> 2) ^ (t & 7)) << 2) + (cp & 3)] = pack_bf16(f0, f1);
        }
    } else {                              // ---- V pass-through (swizzle only)
        const int b3 = b - 1024;
        const int head = b3 >> 5, st = b3 & 31;
        const float* src = qkv + (size_t)head * 192 * T_LEN + (size_t)128 * T_LEN;
        const int s0 = st * 64;
        unsigned* dst = (unsigned*)(ws + 16777216) + (size_t)b3 * 2048;
#pragma unroll
        for (int i = 0; i < 8; ++i) {
            int p = i * 256 + tid;
            int s2 = p & 31, c = p >> 5;
            float2 v = *(const float2*)(src + (size_t)c * T_LEN + s0 + 2 * s2);
            dst[c * 32 + (((s2 >> 2) ^ (c & 7)) << 2) + (s2 & 3)] = pack_bf16(v.x, v.y);
        }
    }
}

// ---------------------------------------------------------------------------
// Main: flash attention, 32x32x16 MFMA, operand-swapped QK, permlane exchange.
// RESTRUCTURED vs R6 (same math, same layouts, same LDS): 8 waves x 512 thr
// per block instead of 4 x 256. Wave (wt2, wsx) owns a 32t x 32s tile:
//   wt2 = wave & 3  (t-quarter: t = wt2*32 + l31)     [was wt*64 + tt*32]
//   wsx = wave >> 2 (s-half: s = wsx*32 + pat)        [was wave >> 1]
// Per-wave work halves; waves/CU 8 -> 16 (4/SIMD) for latency hiding.
// ---------------------------------------------------------------------------
__global__ __launch_bounds__(512, 4)
void attn_fwd(const char* __restrict__ ws, float* __restrict__ out)
{
    __shared__ char smem[50176];
    // [0,16384)  Qs        (dead after qf load; epilogue O-combine buffer)
    // [16384,32768) Ks[2]  (8 KB each)
    // [32768,49152) Vs[2]
    // [49152,50176) Lb: 2 x 128 floats

    const int tid  = threadIdx.x;
    const int wave = tid >> 6, lane = tid & 63;
    const int l31  = lane & 31, h = lane >> 5;
    const int wt2  = wave & 3;          // t-quarter (32 t)
    const int wsx  = wave >> 2;         // s-half (32 s per iter)
    const int head = blockIdx.x & 31, tb = blockIdx.x >> 5;
    const int swq  = l31 & 7;

    const char* qsrc = ws + (size_t)head * 262144 + (size_t)tb * 16384;
    const char* ksrc = ws + 8388608  + (size_t)head * 262144;
    const char* vsrc = ws + 16777216 + (size_t)head * 262144;

    char*  Qs = smem;
    char*  Ks = smem + 16384;
    char*  Vs = smem + 32768;
    float* Lb = (float*)(smem + 49152);
    float* Ob = (float*)smem;           // 64c x 128t fp32, aliases Qs+Ks

    // stage Q (16 KB, 16 chunks over 8 waves) + K/V tile 0 (8 chunks each)
#pragma unroll
    for (int n = 0; n < 2; ++n) {
        int ch = wave * 2 + n;
        async16(qsrc + ch * 1024 + lane * 16, Qs + ch * 1024);
    }
    async16(ksrc + wave * 1024 + lane * 16, Ks + wave * 1024);
    async16(vsrc + wave * 1024 + lane * 16, Vs + wave * 1024);
    __syncthreads();

    // Q fragments (B operand): B[n=t=l31][k=c=8h+j], rows t = wt2*32 + l31
    bf16x8 qf[4];
#pragma unroll
    for (int kb = 0; kb < 4; ++kb)
        qf[kb] = *(const bf16x8*)(Qs + (wt2 * 32 + l31) * 128
                                  + (((kb * 2 + h) ^ swq) << 4));

    f32x16 acc[2];                      // [ct], D = O^T[c][t] partial (s-half)
#pragma unroll
    for (int ct = 0; ct < 2; ++ct)
#pragma unroll
        for (int r = 0; r < 16; ++r) acc[ct][r] = 0.f;
    float lp = 0.f;

    for (int i = 0; i < 32; ++i) {
        const int cur = i & 1, nxt = cur ^ 1;
        if (i) __syncthreads();
        if (i < 31) {
            async16(ksrc + (i + 1) * 8192 + wave * 1024 + lane * 16,
                    Ks + nxt * 8192 + wave * 1024);
            async16(vsrc + (i + 1) * 8192 + wave * 1024 + lane * 16,
                    Vs + nxt * 8192 + wave * 1024);
        }

        // ---- QK^T (A=K): S^T rows s = wsx*32 + pat, cols t (this t-quarter)
        const char* KsB = Ks + cur * 8192;
        const char* VsB = Vs + cur * 8192;
        f32x16 sc;
#pragma unroll
        for (int r = 0; r < 16; ++r) sc[r] = 0.f;
        const int krow = (wsx * 32 + l31) * 128;
#pragma unroll
        for (int kb = 0; kb < 4; ++kb) {
            bf16x8 kf = *(const bf16x8*)(KsB + krow + (((kb * 2 + h) ^ swq) << 4));
            sc = __builtin_amdgcn_mfma_f32_32x32x16_bf16(kf, qf[kb], sc, 0, 0, 0);
        }

        // ---- softmax (scores pre-scaled by log2e -> raw 2^x) + bf16
        // truncation pack. l accumulated from TRUNCATED values.
        union P8 { unsigned u[8]; bf16x8 v[2]; };
        P8 P;
#pragma unroll
        for (int d = 0; d < 8; ++d) {
            unsigned a0 = __float_as_uint(fexp2(sc[2 * d]))     & 0xffff0000u;
            unsigned a1 = __float_as_uint(fexp2(sc[2 * d + 1])) & 0xffff0000u;
            lp += __uint_as_float(a0) + __uint_as_float(a1);
            P.u[d] = __builtin_amdgcn_perm(a1, a0, 0x07060302u);
        }

        // ---- lane-half exchange (verified R6 semantics), in place
        swap32(P.u[0], P.u[2]); swap32(P.u[1], P.u[3]);
        swap32(P.u[4], P.u[6]); swap32(P.u[5], P.u[7]);

        // ---- PV: O^T[c][t] += V[c][s] * P[t][s], k = s in this wave's s-half
#pragma unroll
        for (int kb2 = 0; kb2 < 2; ++kb2) {
            const bf16x8 pfv = kb2 ? P.v[1] : P.v[0];
#pragma unroll
            for (int ct = 0; ct < 2; ++ct) {
                bf16x8 vf = *(const bf16x8*)(VsB + (ct * 32 + l31) * 128
                              + (((wsx * 4 + kb2 * 2 + h) ^ swq) << 4));
                acc[ct] = __builtin_amdgcn_mfma_f32_32x32x16_bf16(vf, pfv, acc[ct], 0, 0, 0);
            }
        }
    }

    __syncthreads();                    // drain last iter's LDS reads

    // ---- l: reduce over h, publish per s-half (one wave per (wsx,wt2))
    float lt = lp + __shfl_xor(lp, 32);
    if (h == 0) Lb[wsx * 128 + wt2 * 32 + l31] = lt;

    // ---- O: s-half-1 waves stash partials (aliases dead Qs+Ks)
    if (wsx == 1) {
#pragma unroll
        for (int ct = 0; ct < 2; ++ct)
#pragma unroll
            for (int r = 0; r < 16; ++r) {
                int c = ct * 32 + (r & 3) + 8 * (r >> 2) + 4 * h;
                Ob[c * 128 + wt2 * 32 + l31] = acc[ct][r];
            }
    }
    __syncthreads();

    if (wsx == 0) {
        const float li = 1.0f / (Lb[wt2 * 32 + l31] + Lb[128 + wt2 * 32 + l31]);
#pragma unroll
        for (int ct = 0; ct < 2; ++ct)
#pragma unroll
            for (int r = 0; r < 16; ++r) {
                int c = ct * 32 + (r & 3) + 8 * (r >> 2) + 4 * h;
                float v = acc[ct][r] + Ob[c * 128 + wt2 * 32 + l31];
                out[((size_t)head * 64 + c) * T_LEN + tb * 128 + wt2 * 32 + l31]
                    = v * li;
            }
    }
}

extern "C" void kernel_launch(void* const* d_in, const int* in_sizes, int n_in,
                              void* d_out, int out_size, void* d_ws, size_t ws_size,
                              hipStream_t stream) {
    const float* qkv = (const float*)d_in[0];
    float* out = (float*)d_out;
    char* ws = (char*)d_ws;   // 24 MB
    hipLaunchKernelGGL(prepack, dim3(2048), dim3(256), 0, stream, qkv, ws);
    hipLaunchKernelGGL(attn_fwd, dim3(512), dim3(512), 0, stream, ws, out);
}